// Round 2
// baseline (629.882 us; speedup 1.0000x reference)
//
#include <hip/hip_runtime.h>
#include <hip/hip_bf16.h>

#define NN 4096
#define IN_F 256
#define OUT_F 128
#define ALPHA 0.2f
#define NROWS 4

__device__ __forceinline__ float bf2f(unsigned short u) {
  return __uint_as_float(((unsigned int)u) << 16);
}
__device__ __forceinline__ unsigned short f2bf(float f) {
  union { float f; unsigned int u; } x; x.f = f;
  unsigned int r = x.u + 0x7FFF + ((x.u >> 16) & 1);
  return (unsigned short)(r >> 16);
}

__device__ __forceinline__ float blk_max(float v, float* red) {
  #pragma unroll
  for (int o = 32; o > 0; o >>= 1) v = fmaxf(v, __shfl_down(v, o, 64));
  int wid = threadIdx.x >> 6;
  __syncthreads();
  if ((threadIdx.x & 63) == 0) red[wid] = v;
  __syncthreads();
  return fmaxf(fmaxf(red[0], red[1]), fmaxf(red[2], red[3]));
}
__device__ __forceinline__ float blk_sum(float v, float* red) {
  #pragma unroll
  for (int o = 32; o > 0; o >>= 1) v += __shfl_down(v, o, 64);
  int wid = threadIdx.x >> 6;
  __syncthreads();
  if ((threadIdx.x & 63) == 0) red[wid] = v;
  __syncthreads();
  return red[0] + red[1] + red[2] + red[3];
}

// K1: Whnew[i] = h @ W[i*256:(i+1)*256, :]   -> [3][4096][128] f32
// grid (128, 3), block 256. 32 rows per block, k-tiled by 64 via LDS.
__global__ __launch_bounds__(256) void k_whnew(const float* __restrict__ h,
                                               const float* __restrict__ W,
                                               float* __restrict__ Whnew) {
  const int i = blockIdx.y;
  const int r0 = blockIdx.x * 32;
  const int t = threadIdx.x;
  __shared__ float hs[32][64];
  __shared__ float Ws[64][128];
  const int col = t & 127;
  const int rh = t >> 7;  // 0..1 -> 16 rows each
  float acc[16];
  #pragma unroll
  for (int j = 0; j < 16; ++j) acc[j] = 0.f;
  for (int k0 = 0; k0 < IN_F; k0 += 64) {
    #pragma unroll
    for (int j = 0; j < 8; ++j) {
      int idx = t + j * 256;
      hs[idx >> 6][idx & 63] = h[(size_t)(r0 + (idx >> 6)) * IN_F + k0 + (idx & 63)];
    }
    #pragma unroll
    for (int j = 0; j < 32; ++j) {
      int idx = t + j * 256;
      Ws[idx >> 7][idx & 127] = W[(size_t)(i * IN_F + k0 + (idx >> 7)) * OUT_F + (idx & 127)];
    }
    __syncthreads();
    #pragma unroll 4
    for (int kk = 0; kk < 64; ++kk) {
      float w = Ws[kk][col];
      #pragma unroll
      for (int j = 0; j < 16; ++j) acc[j] += hs[rh * 16 + j][kk] * w;
    }
    __syncthreads();
  }
  #pragma unroll
  for (int j = 0; j < 16; ++j)
    Whnew[((size_t)i * NN + r0 + rh * 16 + j) * OUT_F + col] = acc[j];
}

// K2: Wh1[i][r] = Whnew_i[r,:] . a1_i ; Wh2 likewise; accum = 0.125*Whnew_2
// grid 4096, block 128.
__global__ __launch_bounds__(128) void k_vec(const float* __restrict__ Whnew,
                                             const float* __restrict__ a,
                                             float* __restrict__ Wh1,
                                             float* __restrict__ Wh2,
                                             float* __restrict__ accum) {
  const int r = blockIdx.x;
  const int t = threadIdx.x;
  __shared__ float red1[2], red2[2];
  for (int i = 0; i < 3; ++i) {
    float w = Whnew[((size_t)i * NN + r) * OUT_F + t];
    float v1 = w * a[256 * i + t];
    float v2 = w * a[256 * i + 128 + t];
    #pragma unroll
    for (int o = 32; o > 0; o >>= 1) {
      v1 += __shfl_down(v1, o, 64);
      v2 += __shfl_down(v2, o, 64);
    }
    int wid = t >> 6;
    if ((t & 63) == 0) { red1[wid] = v1; red2[wid] = v2; }
    __syncthreads();
    if (t == 0) {
      Wh1[i * NN + r] = red1[0] + red1[1];
      Wh2[i * NN + r] = red2[0] + red2[1];
    }
    if (i == 2) accum[(size_t)r * OUT_F + t] = 0.125f * w;
    __syncthreads();
  }
}

// K3: per (hop i, 4 rows): masked softmax over 4096 cols (rank-1 scores,
// recomputed in regs), probs stored bf16 in LDS, then out += coef * att @ Whnew_i.
// grid (1024, 3), block 256.
__global__ __launch_bounds__(256) void k_attn(const float* __restrict__ Whnew,
                                              const int* __restrict__ mask,
                                              const float* __restrict__ Wh1,
                                              const float* __restrict__ Wh2,
                                              float* __restrict__ accum) {
  const int i = blockIdx.y;
  const int r0 = blockIdx.x * NROWS;
  const int t = threadIdx.x;
  __shared__ unsigned short p[NROWS][NN];  // 32 KiB, post-exp probs (bf16)
  __shared__ float red[4];
  __shared__ float sinv[NROWS];
  __shared__ float part[NROWS][128];
  const float coef = (i == 0) ? 0.5f : (i == 1) ? 0.25f : 0.125f;
  const float* Wn = Whnew + (size_t)i * NN * OUT_F;
  const float* wh2 = Wh2 + i * NN;

  for (int rr = 0; rr < NROWS; ++rr) {
    const int r = r0 + rr;
    const float wh1 = Wh1[i * NN + r];
    const int* mrow = mask + ((size_t)i * NN + r) * NN;
    float ev[16];
    float m = -3.0e38f;
    #pragma unroll
    for (int j = 0; j < 16; ++j) {
      int c = t + j * 256;
      float e = wh1 + wh2[c];
      e = (e > 0.f) ? e : ALPHA * e;
      float v = (mrow[c] > 0) ? e : -3.0e38f;
      ev[j] = v;
      m = fmaxf(m, v);
    }
    m = blk_max(m, red);
    float s = 0.f;
    #pragma unroll
    for (int j = 0; j < 16; ++j) {
      int c = t + j * 256;
      float pe = expf(ev[j] - m);
      s += pe;
      p[rr][c] = f2bf(pe);
    }
    s = blk_sum(s, red);
    if (t == 0) sinv[rr] = 1.0f / s;
  }
  __syncthreads();

  const int col = t & 127;
  const int half = t >> 7;
  float acc[NROWS] = {0.f, 0.f, 0.f, 0.f};
  const int cbeg = half * (NN / 2);
  for (int c = cbeg; c < cbeg + NN / 2; c += 4) {
    float w0 = Wn[(size_t)(c + 0) * OUT_F + col];
    float w1 = Wn[(size_t)(c + 1) * OUT_F + col];
    float w2 = Wn[(size_t)(c + 2) * OUT_F + col];
    float w3 = Wn[(size_t)(c + 3) * OUT_F + col];
    #pragma unroll
    for (int rr = 0; rr < NROWS; ++rr) {
      ushort4 pv = *reinterpret_cast<const ushort4*>(&p[rr][c]);
      acc[rr] = fmaf(bf2f(pv.x), w0,
                fmaf(bf2f(pv.y), w1,
                fmaf(bf2f(pv.z), w2,
                fmaf(bf2f(pv.w), w3, acc[rr]))));
    }
  }
  if (half == 1) {
    #pragma unroll
    for (int rr = 0; rr < NROWS; ++rr) part[rr][col] = acc[rr];
  }
  __syncthreads();
  if (half == 0) {
    #pragma unroll
    for (int rr = 0; rr < NROWS; ++rr) {
      float v = (acc[rr] + part[rr][col]) * sinv[rr] * coef;
      atomicAdd(&accum[(size_t)(r0 + rr) * OUT_F + col], v);
    }
  }
}

// K4: out = elu(accum), in place (accum aliases d_out).
__global__ __launch_bounds__(256) void k_elu(float* __restrict__ out) {
  int idx = blockIdx.x * 256 + threadIdx.x;
  float x = out[idx];
  out[idx] = (x > 0.f) ? x : (expf(x) - 1.0f);
}

extern "C" void kernel_launch(void* const* d_in, const int* in_sizes, int n_in,
                              void* d_out, int out_size, void* d_ws, size_t ws_size,
                              hipStream_t stream) {
  const float* h    = (const float*)d_in[0];
  const int*   mask = (const int*)d_in[1];
  const float* W    = (const float*)d_in[2];
  const float* a    = (const float*)d_in[3];
  float* out = (float*)d_out;

  float* Whnew = (float*)d_ws;                   // 3*4096*128 f32 = 6 MiB
  float* Wh1   = Whnew + (size_t)3 * NN * OUT_F; // 3*4096
  float* Wh2   = Wh1 + 3 * NN;                   // 3*4096

  k_whnew<<<dim3(128, 3), 256, 0, stream>>>(h, W, Whnew);
  k_vec<<<NN, 128, 0, stream>>>(Whnew, a, Wh1, Wh2, out);
  k_attn<<<dim3(NN / NROWS, 3), 256, 0, stream>>>(Whnew, mask, Wh1, Wh2, out);
  k_elu<<<(NN * OUT_F) / 256, 256, 0, stream>>>(out);
}

// Round 3
// 480.379 us; speedup vs baseline: 1.3112x; 1.3112x over previous
//
#include <hip/hip_runtime.h>
#include <hip/hip_bf16.h>

#define NN 4096
#define IN_F 256
#define OUT_F 128
#define ALPHA 0.2f

typedef __bf16 bf16x8 __attribute__((ext_vector_type(8)));
typedef float f32x4 __attribute__((ext_vector_type(4)));

__device__ __forceinline__ unsigned short f2bf(float f) {
  union { float f; unsigned int u; } x; x.f = f;
  unsigned int r = x.u + 0x7FFF + ((x.u >> 16) & 1);
  return (unsigned short)(r >> 16);
}

// K1: Whnew[i] = h @ W[i*256:(i+1)*256, :]   -> [3][4096][128] f32  (unchanged)
__global__ __launch_bounds__(256) void k_whnew(const float* __restrict__ h,
                                               const float* __restrict__ W,
                                               float* __restrict__ Whnew) {
  const int i = blockIdx.y;
  const int r0 = blockIdx.x * 32;
  const int t = threadIdx.x;
  __shared__ float hs[32][64];
  __shared__ float Ws[64][128];
  const int col = t & 127;
  const int rh = t >> 7;
  float acc[16];
  #pragma unroll
  for (int j = 0; j < 16; ++j) acc[j] = 0.f;
  for (int k0 = 0; k0 < IN_F; k0 += 64) {
    #pragma unroll
    for (int j = 0; j < 8; ++j) {
      int idx = t + j * 256;
      hs[idx >> 6][idx & 63] = h[(size_t)(r0 + (idx >> 6)) * IN_F + k0 + (idx & 63)];
    }
    #pragma unroll
    for (int j = 0; j < 32; ++j) {
      int idx = t + j * 256;
      Ws[idx >> 7][idx & 127] = W[(size_t)(i * IN_F + k0 + (idx >> 7)) * OUT_F + (idx & 127)];
    }
    __syncthreads();
    #pragma unroll 4
    for (int kk = 0; kk < 64; ++kk) {
      float w = Ws[kk][col];
      #pragma unroll
      for (int j = 0; j < 16; ++j) acc[j] += hs[rh * 16 + j][kk] * w;
    }
    __syncthreads();
  }
  #pragma unroll
  for (int j = 0; j < 16; ++j)
    Whnew[((size_t)i * NN + r0 + rh * 16 + j) * OUT_F + col] = acc[j];
}

// K2: Wh1/Wh2 vectors; seed accum = 0.125*Whnew_2  (unchanged)
__global__ __launch_bounds__(128) void k_vec(const float* __restrict__ Whnew,
                                             const float* __restrict__ a,
                                             float* __restrict__ Wh1,
                                             float* __restrict__ Wh2,
                                             float* __restrict__ accum) {
  const int r = blockIdx.x;
  const int t = threadIdx.x;
  __shared__ float red1[2], red2[2];
  for (int i = 0; i < 3; ++i) {
    float w = Whnew[((size_t)i * NN + r) * OUT_F + t];
    float v1 = w * a[256 * i + t];
    float v2 = w * a[256 * i + 128 + t];
    #pragma unroll
    for (int o = 32; o > 0; o >>= 1) {
      v1 += __shfl_down(v1, o, 64);
      v2 += __shfl_down(v2, o, 64);
    }
    int wid = t >> 6;
    if ((t & 63) == 0) { red1[wid] = v1; red2[wid] = v2; }
    __syncthreads();
    if (t == 0) {
      Wh1[i * NN + r] = red1[0] + red1[1];
      Wh2[i * NN + r] = red2[0] + red2[1];
    }
    if (i == 2) accum[(size_t)r * OUT_F + t] = 0.125f * w;
    __syncthreads();
  }
}

// K2b: gmax2[i] = max_c Wh2[i][c]
__global__ __launch_bounds__(256) void k_gmax(const float* __restrict__ Wh2,
                                              float* __restrict__ gmax2) {
  const int i = blockIdx.x;
  const int t = threadIdx.x;
  __shared__ float red[4];
  float m = -3.0e38f;
  #pragma unroll
  for (int j = 0; j < 16; ++j) m = fmaxf(m, Wh2[i * NN + t + j * 256]);
  #pragma unroll
  for (int o = 32; o > 0; o >>= 1) m = fmaxf(m, __shfl_down(m, o, 64));
  if ((t & 63) == 0) red[t >> 6] = m;
  __syncthreads();
  if (t == 0) gmax2[i] = fmaxf(fmaxf(red[0], red[1]), fmaxf(red[2], red[3]));
}

// K2c: Vt[i][n][k] = bf16(Whnew[i][k][n])  (k-major for MFMA B-frag loads)
__global__ __launch_bounds__(256) void k_cvt(const float* __restrict__ Whnew,
                                             unsigned short* __restrict__ Vt) {
  const int i = blockIdx.y;
  const int k0 = blockIdx.x * 32;
  const int t = threadIdx.x;
  __shared__ float tile[32][129];
  #pragma unroll
  for (int j = 0; j < 16; ++j) {
    int idx = t + j * 256;
    int r = idx >> 7, c = idx & 127;
    tile[r][c] = Whnew[((size_t)i * NN + k0 + r) * OUT_F + c];
  }
  __syncthreads();
  const int c = t >> 1, half = t & 1;
  unsigned short* dst = Vt + ((size_t)i * OUT_F + c) * NN + k0 + half * 16;
  #pragma unroll
  for (int g = 0; g < 4; ++g) {
    ushort4 v;
    v.x = f2bf(tile[half * 16 + g * 4 + 0][c]);
    v.y = f2bf(tile[half * 16 + g * 4 + 1][c]);
    v.z = f2bf(tile[half * 16 + g * 4 + 2][c]);
    v.w = f2bf(tile[half * 16 + g * 4 + 3][c]);
    *(ushort4*)(dst + g * 4) = v;
  }
}

// K3: MFMA attention. Block = 32 rows of hop i. One pass over k:
// scores -> p=exp(lrelu-mx) bf16 in swizzled LDS (dbuf), row-sum via ones-MFMA,
// C += P @ Vt. Epilogue scales by coef/srow and atomically adds into accum.
__global__ __launch_bounds__(256) void k_attn(const unsigned short* __restrict__ Vt,
                                              const int* __restrict__ mask,
                                              const float* __restrict__ Wh1,
                                              const float* __restrict__ Wh2,
                                              const float* __restrict__ gmax2,
                                              float* __restrict__ accum) {
  const int i = blockIdx.y;
  const int r0 = blockIdx.x * 32;
  const int t = threadIdx.x;
  const int lane = t & 63;
  const int wid = t >> 6;
  const int m = wid & 1;          // M-frag (rows m*16..m*16+15)
  const int nbase = (wid >> 1) * 64;  // this wave's 64-col slab
  const int ln = lane & 15;
  const int lk = lane >> 4;       // 0..3

  __shared__ unsigned short P[2][32 * 128];  // bf16 probs, XOR-swizzled
  __shared__ float wh1s[32], mxs[32], srow[32];

  if (t < 32) {
    float w1 = Wh1[i * NN + r0 + t];
    wh1s[t] = w1;
    float e = w1 + gmax2[i];
    mxs[t] = (e > 0.f) ? e : ALPHA * e;
  }
  __syncthreads();

  const float coef = (i == 0) ? 0.5f : (i == 1) ? 0.25f : 0.125f;
  const int* mbase = mask + ((size_t)i * NN + r0) * NN;
  const float* wh2 = Wh2 + i * NN;

  // B pointers (k-major bf16 V), one per 16-col n-frag
  const unsigned short* bp0 = Vt + ((size_t)i * OUT_F + nbase +  0 + ln) * NN + lk * 8;
  const unsigned short* bp1 = Vt + ((size_t)i * OUT_F + nbase + 16 + ln) * NN + lk * 8;
  const unsigned short* bp2 = Vt + ((size_t)i * OUT_F + nbase + 32 + ln) * NN + lk * 8;
  const unsigned short* bp3 = Vt + ((size_t)i * OUT_F + nbase + 48 + ln) * NN + lk * 8;

  const int arow = m * 16 + ln;
  const int abase = arow * 256;
  const int axor = (arow & 7) << 4;

  f32x4 z4 = {0.f, 0.f, 0.f, 0.f};
  f32x4 acc0 = z4, acc1 = z4, acc2 = z4, acc3 = z4, accS = z4;
  bf16x8 ones = {(__bf16)1.0f, (__bf16)1.0f, (__bf16)1.0f, (__bf16)1.0f,
                 (__bf16)1.0f, (__bf16)1.0f, (__bf16)1.0f, (__bf16)1.0f};

  int4 mk[4];
  float4 w2[4];

  auto LOADM = [&](int c) {
    const int k0 = c * 128;
    #pragma unroll
    for (int j = 0; j < 4; ++j) {
      int idx = t * 4 + j * 1024;
      int r = idx >> 7, dc = idx & 127;
      mk[j] = *(const int4*)(mbase + (size_t)r * NN + k0 + dc);
      w2[j] = *(const float4*)(wh2 + k0 + dc);
    }
  };
  auto COMP = [&](int buf) {
    #pragma unroll
    for (int j = 0; j < 4; ++j) {
      int idx = t * 4 + j * 1024;
      int r = idx >> 7, dc = idx & 127;
      float w1 = wh1s[r], mx = mxs[r];
      float e0 = w1 + w2[j].x; e0 = (e0 > 0.f) ? e0 : ALPHA * e0;
      float e1 = w1 + w2[j].y; e1 = (e1 > 0.f) ? e1 : ALPHA * e1;
      float e2 = w1 + w2[j].z; e2 = (e2 > 0.f) ? e2 : ALPHA * e2;
      float e3 = w1 + w2[j].w; e3 = (e3 > 0.f) ? e3 : ALPHA * e3;
      ushort4 pv;
      pv.x = (mk[j].x > 0) ? f2bf(__expf(e0 - mx)) : 0;
      pv.y = (mk[j].y > 0) ? f2bf(__expf(e1 - mx)) : 0;
      pv.z = (mk[j].z > 0) ? f2bf(__expf(e2 - mx)) : 0;
      pv.w = (mk[j].w > 0) ? f2bf(__expf(e3 - mx)) : 0;
      *(ushort4*)((char*)&P[buf][0] + ((r * 256 + dc * 2) ^ ((r & 7) << 4))) = pv;
    }
  };

  LOADM(0);
  COMP(0);
  __syncthreads();
  LOADM(1);

  for (int c = 0; c < 32; ++c) {
    const int cur = c & 1;
    const int k0 = c * 128;
    #pragma unroll
    for (int ks = 0; ks < 4; ++ks) {
      bf16x8 a = *(const bf16x8*)((const char*)&P[cur][0]
                                  + ((abase + lk * 16 + ks * 64) ^ axor));
      const int koff = k0 + ks * 32;
      acc0 = __builtin_amdgcn_mfma_f32_16x16x32_bf16(a, *(const bf16x8*)(bp0 + koff), acc0, 0, 0, 0);
      acc1 = __builtin_amdgcn_mfma_f32_16x16x32_bf16(a, *(const bf16x8*)(bp1 + koff), acc1, 0, 0, 0);
      acc2 = __builtin_amdgcn_mfma_f32_16x16x32_bf16(a, *(const bf16x8*)(bp2 + koff), acc2, 0, 0, 0);
      acc3 = __builtin_amdgcn_mfma_f32_16x16x32_bf16(a, *(const bf16x8*)(bp3 + koff), acc3, 0, 0, 0);
      accS = __builtin_amdgcn_mfma_f32_16x16x32_bf16(a, ones, accS, 0, 0, 0);
    }
    if (c < 31) COMP(cur ^ 1);
    __syncthreads();
    if (c < 30) LOADM(c + 2);
  }

  // row sums -> LDS (waves 0,1 cover rows 0..31; waves 2,3 are duplicates)
  if (wid < 2 && ln == 0) {
    #pragma unroll
    for (int q = 0; q < 4; ++q) srow[m * 16 + lk * 4 + q] = accS[q];
  }
  __syncthreads();

  #pragma unroll
  for (int q = 0; q < 4; ++q) {
    const int r = m * 16 + lk * 4 + q;
    const float sc = coef / srow[r];
    float* orow = accum + (size_t)(r0 + r) * OUT_F + nbase + ln;
    atomicAdd(orow +  0, acc0[q] * sc);
    atomicAdd(orow + 16, acc1[q] * sc);
    atomicAdd(orow + 32, acc2[q] * sc);
    atomicAdd(orow + 48, acc3[q] * sc);
  }
}

// K4: out = elu(accum), in place
__global__ __launch_bounds__(256) void k_elu(float* __restrict__ out) {
  int idx = blockIdx.x * 256 + threadIdx.x;
  float x = out[idx];
  out[idx] = (x > 0.f) ? x : (expf(x) - 1.0f);
}

extern "C" void kernel_launch(void* const* d_in, const int* in_sizes, int n_in,
                              void* d_out, int out_size, void* d_ws, size_t ws_size,
                              hipStream_t stream) {
  const float* h    = (const float*)d_in[0];
  const int*   mask = (const int*)d_in[1];
  const float* W    = (const float*)d_in[2];
  const float* a    = (const float*)d_in[3];
  float* out = (float*)d_out;

  float* Whnew = (float*)d_ws;                    // 3*4096*128 f32
  float* Wh1   = Whnew + (size_t)3 * NN * OUT_F;  // 3*4096
  float* Wh2   = Wh1 + 3 * NN;                    // 3*4096
  float* gmax2 = Wh2 + 3 * NN;                    // 4 (padded)
  unsigned short* Vt = (unsigned short*)(gmax2 + 4);  // 3*128*4096 bf16

  k_whnew<<<dim3(128, 3), 256, 0, stream>>>(h, W, Whnew);
  k_vec<<<NN, 128, 0, stream>>>(Whnew, a, Wh1, Wh2, out);
  k_gmax<<<3, 256, 0, stream>>>(Wh2, gmax2);
  k_cvt<<<dim3(128, 3), 256, 0, stream>>>(Whnew, Vt);
  k_attn<<<dim3(128, 3), 256, 0, stream>>>(Vt, mask, Wh1, Wh2, gmax2, out);
  k_elu<<<(NN * OUT_F) / 256, 256, 0, stream>>>(out);
}

// Round 4
// 400.683 us; speedup vs baseline: 1.5720x; 1.1989x over previous
//
#include <hip/hip_runtime.h>
#include <hip/hip_bf16.h>

#define NN 4096
#define IN_F 256
#define OUT_F 128
#define ALPHA 0.2f

typedef __bf16 bf16x8 __attribute__((ext_vector_type(8)));
typedef float f32x4 __attribute__((ext_vector_type(4)));

__device__ __forceinline__ unsigned short f2bf(float f) {
  union { float f; unsigned int u; } x; x.f = f;
  unsigned int r = x.u + 0x7FFF + ((x.u >> 16) & 1);
  return (unsigned short)(r >> 16);
}

// ---- converts ----
// hb[r][k] = bf16(h[r][k])
__global__ __launch_bounds__(256) void k_cvt_h(const float* __restrict__ h,
                                               unsigned short* __restrict__ hb) {
  int idx = (blockIdx.x * 256 + threadIdx.x) * 8;
  float4 v0 = *(const float4*)(h + idx);
  float4 v1 = *(const float4*)(h + idx + 4);
  union { unsigned short u[8]; uint4 q; } o;
  o.u[0] = f2bf(v0.x); o.u[1] = f2bf(v0.y); o.u[2] = f2bf(v0.z); o.u[3] = f2bf(v0.w);
  o.u[4] = f2bf(v1.x); o.u[5] = f2bf(v1.y); o.u[6] = f2bf(v1.z); o.u[7] = f2bf(v1.w);
  *(uint4*)(hb + idx) = o.q;
}

// Wtb[i][c][k] = bf16(W[i*256+k][c])   (k-major per output col)
__global__ __launch_bounds__(256) void k_cvt_w(const float* __restrict__ W,
                                               unsigned short* __restrict__ Wtb) {
  const int i = blockIdx.y;
  const int k0 = blockIdx.x * 32;
  const int t = threadIdx.x;
  __shared__ float tile[32][129];
  #pragma unroll
  for (int j = 0; j < 16; ++j) {
    int idx = t + j * 256;
    int r = idx >> 7, c = idx & 127;
    tile[r][c] = W[(size_t)(i * IN_F + k0 + r) * OUT_F + c];
  }
  __syncthreads();
  const int c = t >> 1, half = t & 1;
  unsigned short* dst = Wtb + ((size_t)i * OUT_F + c) * IN_F + k0 + half * 16;
  #pragma unroll
  for (int g = 0; g < 4; ++g) {
    ushort4 v;
    v.x = f2bf(tile[half * 16 + g * 4 + 0][c]);
    v.y = f2bf(tile[half * 16 + g * 4 + 1][c]);
    v.z = f2bf(tile[half * 16 + g * 4 + 2][c]);
    v.w = f2bf(tile[half * 16 + g * 4 + 3][c]);
    *(ushort4*)(dst + g * 4) = v;
  }
}

// ---- zero U and S (contiguous) ----
__global__ __launch_bounds__(256) void k_zero(float* __restrict__ p) {
  int idx = blockIdx.x * 256 + threadIdx.x;
  f32x4 z = {0.f, 0.f, 0.f, 0.f};
  *(f32x4*)(p + (size_t)idx * 4) = z;
}

// ---- K1 fused: Whnew_i = h@W_i via MFMA; emit Vt (bf16, k-major), Wh1/Wh2,
//      and Whnew2 (f32, hop 2 only). grid (128,3), block 256. ----
__global__ __launch_bounds__(256) void k_front(const unsigned short* __restrict__ hb,
                                               const unsigned short* __restrict__ Wtb,
                                               const float* __restrict__ a,
                                               float* __restrict__ Whnew2,
                                               unsigned short* __restrict__ Vt,
                                               float* __restrict__ Wh1,
                                               float* __restrict__ Wh2) {
  const int i = blockIdx.y;
  const int r0 = blockIdx.x * 32;
  const int t = threadIdx.x;
  const int lane = t & 63, wid = t >> 6;
  const int m = wid & 1, nh = wid >> 1, nbase = nh * 64;
  const int ln = lane & 15, lk = lane >> 4;

  __shared__ float a1s[128], a2s[128];
  __shared__ unsigned short tT[128][34];
  __shared__ float red1[2][32], red2[2][32];

  if (t < 128) {
    a1s[t] = a[(size_t)2 * i * OUT_F + t];
    a2s[t] = a[(size_t)(2 * i + 1) * OUT_F + t];
  }
  __syncthreads();

  const unsigned short* ap = hb + (size_t)(r0 + m * 16 + ln) * IN_F + lk * 8;
  const unsigned short* bp = Wtb + ((size_t)i * OUT_F + nbase + ln) * IN_F + lk * 8;

  f32x4 z4 = {0.f, 0.f, 0.f, 0.f};
  f32x4 acc[4] = {z4, z4, z4, z4};
  #pragma unroll
  for (int ks = 0; ks < 8; ++ks) {
    bf16x8 av = *(const bf16x8*)(ap + ks * 32);
    acc[0] = __builtin_amdgcn_mfma_f32_16x16x32_bf16(av, *(const bf16x8*)(bp + 0 * 16 * IN_F + ks * 32), acc[0], 0, 0, 0);
    acc[1] = __builtin_amdgcn_mfma_f32_16x16x32_bf16(av, *(const bf16x8*)(bp + 1 * 16 * IN_F + ks * 32), acc[1], 0, 0, 0);
    acc[2] = __builtin_amdgcn_mfma_f32_16x16x32_bf16(av, *(const bf16x8*)(bp + 2 * 16 * IN_F + ks * 32), acc[2], 0, 0, 0);
    acc[3] = __builtin_amdgcn_mfma_f32_16x16x32_bf16(av, *(const bf16x8*)(bp + 3 * 16 * IN_F + ks * 32), acc[3], 0, 0, 0);
  }

  // epilogue: per lane, rows m*16+lk*4+q (q=0..3), cols nbase+f*16+ln
  float d1[4] = {0.f, 0.f, 0.f, 0.f}, d2[4] = {0.f, 0.f, 0.f, 0.f};
  #pragma unroll
  for (int f = 0; f < 4; ++f) {
    const int col = nbase + f * 16 + ln;
    const float va1 = a1s[col], va2 = a2s[col];
    #pragma unroll
    for (int q = 0; q < 4; ++q) {
      const int row = m * 16 + lk * 4 + q;
      const float v = acc[f][q];
      if (i == 2) Whnew2[(size_t)(r0 + row) * OUT_F + col] = v;
      tT[col][row] = f2bf(v);
      d1[q] += v * va1;
      d2[q] += v * va2;
    }
  }
  #pragma unroll
  for (int msk = 1; msk < 16; msk <<= 1) {
    #pragma unroll
    for (int q = 0; q < 4; ++q) {
      d1[q] += __shfl_xor(d1[q], msk, 64);
      d2[q] += __shfl_xor(d2[q], msk, 64);
    }
  }
  if (ln == 0) {
    #pragma unroll
    for (int q = 0; q < 4; ++q) {
      red1[nh][m * 16 + lk * 4 + q] = d1[q];
      red2[nh][m * 16 + lk * 4 + q] = d2[q];
    }
  }
  __syncthreads();

  if (t < 32) {
    Wh1[(size_t)i * NN + r0 + t] = red1[0][t] + red1[1][t];
    Wh2[(size_t)i * NN + r0 + t] = red2[0][t] + red2[1][t];
  }
  // Vt store: c = t>>1, half = t&1: 16 contiguous k
  {
    const int c = t >> 1, half = t & 1;
    unsigned short* dst = Vt + ((size_t)i * OUT_F + c) * NN + r0 + half * 16;
    union { unsigned short u[8]; uint4 q; } o0, o1;
    #pragma unroll
    for (int j = 0; j < 8; ++j) { o0.u[j] = tT[c][half * 16 + j]; o1.u[j] = tT[c][half * 16 + 8 + j]; }
    *(uint4*)(dst) = o0.q;
    *(uint4*)(dst + 8) = o1.q;
  }
}

// ---- gmax2[i] = max_c Wh2[i][c] ----
__global__ __launch_bounds__(256) void k_gmax(const float* __restrict__ Wh2,
                                              float* __restrict__ gmax2) {
  const int i = blockIdx.x;
  const int t = threadIdx.x;
  __shared__ float red[4];
  float m = -3.0e38f;
  #pragma unroll
  for (int j = 0; j < 16; ++j) m = fmaxf(m, Wh2[(size_t)i * NN + t + j * 256]);
  #pragma unroll
  for (int o = 32; o > 0; o >>= 1) m = fmaxf(m, __shfl_down(m, o, 64));
  if ((t & 63) == 0) red[t >> 6] = m;
  __syncthreads();
  if (t == 0) gmax2[i] = fmaxf(fmaxf(red[0], red[1]), fmaxf(red[2], red[3]));
}

// ---- K3: column-split MFMA attention. grid (128, 3, 4). Block: 32 rows x 1024 cols.
// Accumulates unnormalized U += P@V (atomic) and S += rowsum(P) (atomic). ----
__global__ __launch_bounds__(256) void k_attn(const unsigned short* __restrict__ Vt,
                                              const int* __restrict__ mask,
                                              const float* __restrict__ Wh1,
                                              const float* __restrict__ Wh2,
                                              const float* __restrict__ gmax2,
                                              float* __restrict__ U,
                                              float* __restrict__ S) {
  const int i = blockIdx.y;
  const int r0 = blockIdx.x * 32;
  const int c0 = blockIdx.z * (NN / 4);
  const int t = threadIdx.x;
  const int lane = t & 63, wid = t >> 6;
  const int m = wid & 1, nh = wid >> 1, nbase = nh * 64;
  const int ln = lane & 15, lk = lane >> 4;

  __shared__ unsigned short P[2][32 * 128];
  __shared__ float wh1s[32], mxs[32];

  if (t < 32) {
    float w1 = Wh1[(size_t)i * NN + r0 + t];
    wh1s[t] = w1;
    float e = w1 + gmax2[i];
    mxs[t] = (e > 0.f) ? e : ALPHA * e;
  }
  __syncthreads();

  const int* mbase = mask + ((size_t)i * NN + r0) * NN + c0;
  const float* wh2 = Wh2 + (size_t)i * NN + c0;

  const unsigned short* bp0 = Vt + ((size_t)i * OUT_F + nbase +  0 + ln) * NN + c0 + lk * 8;
  const unsigned short* bp1 = Vt + ((size_t)i * OUT_F + nbase + 16 + ln) * NN + c0 + lk * 8;
  const unsigned short* bp2 = Vt + ((size_t)i * OUT_F + nbase + 32 + ln) * NN + c0 + lk * 8;
  const unsigned short* bp3 = Vt + ((size_t)i * OUT_F + nbase + 48 + ln) * NN + c0 + lk * 8;

  const int arow = m * 16 + ln;
  const int abase = arow * 256;
  const int axor = (arow & 7) << 4;

  f32x4 z4 = {0.f, 0.f, 0.f, 0.f};
  f32x4 acc0 = z4, acc1 = z4, acc2 = z4, acc3 = z4, accS = z4;
  bf16x8 ones = {(__bf16)1.0f, (__bf16)1.0f, (__bf16)1.0f, (__bf16)1.0f,
                 (__bf16)1.0f, (__bf16)1.0f, (__bf16)1.0f, (__bf16)1.0f};

  int4 mk[4];
  float4 w2[4];

  auto LOADM = [&](int c) {
    const int k0 = c * 128;
    #pragma unroll
    for (int j = 0; j < 4; ++j) {
      int idx = t * 4 + j * 1024;
      int r = idx >> 7, dc = idx & 127;
      mk[j] = *(const int4*)(mbase + (size_t)r * NN + k0 + dc);
      w2[j] = *(const float4*)(wh2 + k0 + dc);
    }
  };
  auto COMP = [&](int buf) {
    #pragma unroll
    for (int j = 0; j < 4; ++j) {
      int idx = t * 4 + j * 1024;
      int r = idx >> 7, dc = idx & 127;
      float w1 = wh1s[r], mx = mxs[r];
      float e0 = w1 + w2[j].x; e0 = (e0 > 0.f) ? e0 : ALPHA * e0;
      float e1 = w1 + w2[j].y; e1 = (e1 > 0.f) ? e1 : ALPHA * e1;
      float e2 = w1 + w2[j].z; e2 = (e2 > 0.f) ? e2 : ALPHA * e2;
      float e3 = w1 + w2[j].w; e3 = (e3 > 0.f) ? e3 : ALPHA * e3;
      ushort4 pv;
      pv.x = (mk[j].x > 0) ? f2bf(__expf(e0 - mx)) : 0;
      pv.y = (mk[j].y > 0) ? f2bf(__expf(e1 - mx)) : 0;
      pv.z = (mk[j].z > 0) ? f2bf(__expf(e2 - mx)) : 0;
      pv.w = (mk[j].w > 0) ? f2bf(__expf(e3 - mx)) : 0;
      *(ushort4*)((char*)&P[buf][0] + ((r * 256 + dc * 2) ^ ((r & 7) << 4))) = pv;
    }
  };

  LOADM(0);
  COMP(0);
  __syncthreads();
  LOADM(1);

  for (int c = 0; c < 8; ++c) {
    const int cur = c & 1;
    const int k0 = c * 128;
    #pragma unroll
    for (int ks = 0; ks < 4; ++ks) {
      bf16x8 av = *(const bf16x8*)((const char*)&P[cur][0]
                                   + ((abase + lk * 16 + ks * 64) ^ axor));
      const int koff = k0 + ks * 32;
      acc0 = __builtin_amdgcn_mfma_f32_16x16x32_bf16(av, *(const bf16x8*)(bp0 + koff), acc0, 0, 0, 0);
      acc1 = __builtin_amdgcn_mfma_f32_16x16x32_bf16(av, *(const bf16x8*)(bp1 + koff), acc1, 0, 0, 0);
      acc2 = __builtin_amdgcn_mfma_f32_16x16x32_bf16(av, *(const bf16x8*)(bp2 + koff), acc2, 0, 0, 0);
      acc3 = __builtin_amdgcn_mfma_f32_16x16x32_bf16(av, *(const bf16x8*)(bp3 + koff), acc3, 0, 0, 0);
      if (nh == 0) accS = __builtin_amdgcn_mfma_f32_16x16x32_bf16(av, ones, accS, 0, 0, 0);
    }
    if (c < 7) COMP(cur ^ 1);
    __syncthreads();
    if (c < 6) LOADM(c + 2);
  }

  if (nh == 0 && ln == 0) {
    #pragma unroll
    for (int q = 0; q < 4; ++q)
      atomicAdd(&S[(size_t)i * NN + r0 + m * 16 + lk * 4 + q], accS[q]);
  }
  #pragma unroll
  for (int q = 0; q < 4; ++q) {
    const int row = m * 16 + lk * 4 + q;
    float* urow = U + ((size_t)i * NN + r0 + row) * OUT_F + nbase + ln;
    atomicAdd(urow +  0, acc0[q]);
    atomicAdd(urow + 16, acc1[q]);
    atomicAdd(urow + 32, acc2[q]);
    atomicAdd(urow + 48, acc3[q]);
  }
}

// ---- final combine: out = elu(0.5 U0/S0 + 0.25 U1/S1 + 0.125 U2/S2 + 0.125 Whnew2) ----
__global__ __launch_bounds__(256) void k_final(const float* __restrict__ U,
                                               const float* __restrict__ S,
                                               const float* __restrict__ Whnew2,
                                               float* __restrict__ out) {
  int idx = blockIdx.x * 256 + threadIdx.x;
  int r = idx >> 7;
  float v = 0.5f   * U[idx] / S[r]
          + 0.25f  * U[(size_t)NN * OUT_F + idx] / S[NN + r]
          + 0.125f * U[(size_t)2 * NN * OUT_F + idx] / S[2 * NN + r]
          + 0.125f * Whnew2[idx];
  out[idx] = (v > 0.f) ? v : (expf(v) - 1.0f);
}

extern "C" void kernel_launch(void* const* d_in, const int* in_sizes, int n_in,
                              void* d_out, int out_size, void* d_ws, size_t ws_size,
                              hipStream_t stream) {
  const float* h    = (const float*)d_in[0];
  const int*   mask = (const int*)d_in[1];
  const float* W    = (const float*)d_in[2];
  const float* a    = (const float*)d_in[3];
  float* out = (float*)d_out;

  float* Whnew2 = (float*)d_ws;                      // NN*128
  float* Wh1    = Whnew2 + (size_t)NN * OUT_F;       // 3*NN
  float* Wh2    = Wh1 + 3 * NN;                      // 3*NN
  float* gmax2  = Wh2 + 3 * NN;                      // 4
  float* U      = gmax2 + 4;                         // 3*NN*128
  float* S      = U + (size_t)3 * NN * OUT_F;        // 3*NN  (contiguous after U)
  unsigned short* hb  = (unsigned short*)(S + 3 * NN);   // NN*256
  unsigned short* Wtb = hb + (size_t)NN * IN_F;          // 3*128*256
  unsigned short* Vt  = Wtb + (size_t)3 * OUT_F * IN_F;  // 3*128*NN

  k_cvt_h<<<512, 256, 0, stream>>>(h, hb);
  k_cvt_w<<<dim3(8, 3), 256, 0, stream>>>(W, Wtb);
  k_zero<<<(3 * NN * OUT_F + 3 * NN) / 1024, 256, 0, stream>>>(U);
  k_front<<<dim3(128, 3), 256, 0, stream>>>(hb, Wtb, a, Whnew2, Vt, Wh1, Wh2);
  k_gmax<<<3, 256, 0, stream>>>(Wh2, gmax2);
  k_attn<<<dim3(128, 3, 4), 256, 0, stream>>>(Vt, mask, Wh1, Wh2, gmax2, U, S);
  k_final<<<(NN * OUT_F) / 256, 256, 0, stream>>>(U, S, Whnew2, out);
}